// Round 5
// baseline (2886.004 us; speedup 1.0000x reference)
//
#include <hip/hip_runtime.h>

// ROIPooler (FPN multi-level ROIAlign, aligned=true), float32 in/out.
// R4: single-kernel direct-from-NCHW gather. Per ROI, the sample window at its
// FPN level is provably <= ~1040 px (bin_w*bin_h < 16 from the level rule), so
// it fits in LDS per 16-channel chunk. Load window rows coalesced -> LDS,
// compute 49 bins from LDS, dump output coalesced. No transpose, no workspace.

#define OUTD 7
#define SRD  2
#define SD   14      // OUTD*SRD samples per axis
#define CCH  256
#define NBOX 256
#define NC   16      // channels per chunk
#define NCH  (CCH / NC)
#define CAPP 1153    // window capacity (floats) per channel; odd -> bank spread
#define NBIN (OUTD * OUTD)

__global__ __launch_bounds__(256, 2) void roi_direct(
    const float* __restrict__ f0, const float* __restrict__ f1,
    const float* __restrict__ f2, const float* __restrict__ f3,
    const float* __restrict__ boxes, float* __restrict__ out)
{
    const int roi = blockIdx.x;
    const int t   = threadIdx.x;
    const int b   = roi / NBOX;

    const float bx1 = boxes[roi * 4 + 0];
    const float by1 = boxes[roi * 4 + 1];
    const float bx2 = boxes[roi * 4 + 2];
    const float by2 = boxes[roi * 4 + 3];

    // Level assignment (block-uniform).
    const float area = (bx2 - bx1) * (by2 - by1);
    const float sz   = sqrtf(area);
    int lvl = (int)floorf(4.0f + log2f(sz * (1.0f / 224.0f) + 1e-8f));
    lvl = min(max(lvl, 2), 5) - 2;

    const int   H     = 256 >> lvl;
    const int   W     = H;
    const float scale = 1.0f / (float)(4 << lvl);
    const size_t HW   = (size_t)H * (size_t)W;

    const float* f  = (lvl == 0) ? f0 : (lvl == 1) ? f1 : (lvl == 2) ? f2 : f3;
    const float* fb = f + (size_t)b * CCH * HW;

    // Sample metadata (absolute coords; validity folded into weights).
    __shared__ int   s_ax0[SD], s_ax1[SD], s_ay0[SD], s_ay1[SD];
    __shared__ float s_wxh[SD], s_wxl[SD], s_wyh[SD], s_wyl[SD];
    __shared__ float s_win[NC * CAPP];   // 73792 B
    __shared__ float s_out[NC * NBIN];   // 3136 B

    if (t < SD) {
        const int i = t;
        const float x1r = bx1 * scale - 0.5f;
        const float y1r = by1 * scale - 0.5f;
        const float x2r = bx2 * scale - 0.5f;
        const float y2r = by2 * scale - 0.5f;
        const float bw = (x2r - x1r) * (1.0f / OUTD);
        const float bh = (y2r - y1r) * (1.0f / OUTD);
        const float g  = ((float)i + 0.5f) * (1.0f / SRD);
        const float ys = y1r + g * bh;
        const float xs = x1r + g * bw;
        const float vy = ((ys >= -1.0f) && (ys <= (float)H)) ? 1.0f : 0.0f;
        const float vx = ((xs >= -1.0f) && (xs <= (float)W)) ? 1.0f : 0.0f;
        const float yc = fminf(fmaxf(ys, 0.0f), (float)(H - 1));
        const float xc = fminf(fmaxf(xs, 0.0f), (float)(W - 1));
        const int y0 = (int)yc;
        const int x0 = (int)xc;
        const float ly = yc - (float)y0;
        const float lx = xc - (float)x0;
        s_ay0[i] = y0;
        s_ay1[i] = min(y0 + 1, H - 1);
        s_ax0[i] = x0;
        s_ax1[i] = min(x0 + 1, W - 1);
        s_wyh[i] = vy * (1.0f - ly);
        s_wyl[i] = vy * ly;
        s_wxh[i] = vx * (1.0f - lx);
        s_wxl[i] = vx * lx;
    }
    __syncthreads();

    // Window bounds (uniform; every thread computes identically via broadcast reads).
    int x_lo = s_ax0[0], x_hi = s_ax1[0], y_lo = s_ay0[0], y_hi = s_ay1[0];
    #pragma unroll
    for (int j = 1; j < SD; ++j) {
        x_lo = min(x_lo, s_ax0[j]); x_hi = max(x_hi, s_ax1[j]);
        y_lo = min(y_lo, s_ay0[j]); y_hi = max(y_hi, s_ay1[j]);
    }
    const int Ww = x_hi - x_lo + 1;
    const int Hw = y_hi - y_lo + 1;

    if (Hw * Ww <= CAPP) {
        // -------- fast path --------
        // Per-thread (c_group, bin) assignment: lanes 0..244 active in compute.
        const int c_idx = t / 49;            // 0..5 (5 => idle)
        const int bin   = t - c_idx * 49;
        const int oy    = bin / 7;
        const int ox    = bin - oy * 7;
        const int ia = 2 * oy, ib = ia + 1;
        const int ja = 2 * ox, jb = ja + 1;

        // Register meta for this thread's bin (chunk-invariant).
        const int ryA0 = (s_ay0[ia] - y_lo) * Ww, ryA1 = (s_ay1[ia] - y_lo) * Ww;
        const int ryB0 = (s_ay0[ib] - y_lo) * Ww, ryB1 = (s_ay1[ib] - y_lo) * Ww;
        const int rxA0 = s_ax0[ja] - x_lo,        rxA1 = s_ax1[ja] - x_lo;
        const int rxB0 = s_ax0[jb] - x_lo,        rxB1 = s_ax1[jb] - x_lo;
        const float wyAh = s_wyh[ia], wyAl = s_wyl[ia];
        const float wyBh = s_wyh[ib], wyBl = s_wyl[ib];
        const float wxAh = s_wxh[ja], wxAl = s_wxl[ja];
        const float wxBh = s_wxh[jb], wxBl = s_wxl[jb];

        const int wave  = t >> 6;    // 0..3
        const int lane  = t & 63;
        const int nruns = NC * Hw;   // runs: run = y*NC + c

        for (int ch = 0; ch < NCH; ++ch) {
            const int c0 = ch * NC;
            // Load window rows for channels [c0, c0+NC): contiguous x-runs.
            for (int run = wave; run < nruns; run += 4) {
                const int c = run & (NC - 1);
                const int y = run >> 4;
                const float* src = fb + (size_t)(c0 + c) * HW
                                      + (size_t)(y_lo + y) * W + x_lo;
                float* dst = s_win + c * CAPP + y * Ww;
                for (int x = lane; x < Ww; x += 64)
                    dst[x] = src[x];
            }
            __syncthreads();

            // Compute: each active thread does its bin for channels ci = c_idx+5k.
            if (t < 245) {
                for (int ci = c_idx; ci < NC; ci += 5) {
                    const float* w = s_win + ci * CAPP;
                    const float acc =
                        wyAh * (wxAh * w[ryA0 + rxA0] + wxAl * w[ryA0 + rxA1])
                      + wyAl * (wxAh * w[ryA1 + rxA0] + wxAl * w[ryA1 + rxA1])
                      + wyAh * (wxBh * w[ryA0 + rxB0] + wxBl * w[ryA0 + rxB1])
                      + wyAl * (wxBh * w[ryA1 + rxB0] + wxBl * w[ryA1 + rxB1])
                      + wyBh * (wxAh * w[ryB0 + rxA0] + wxAl * w[ryB0 + rxA1])
                      + wyBl * (wxAh * w[ryB1 + rxA0] + wxAl * w[ryB1 + rxA1])
                      + wyBh * (wxBh * w[ryB0 + rxB0] + wxBl * w[ryB0 + rxB1])
                      + wyBl * (wxBh * w[ryB1 + rxB0] + wxBl * w[ryB1 + rxB1]);
                    s_out[ci * NBIN + bin] = acc * 0.25f;
                }
            }
            __syncthreads();

            // Coalesced dump: s_out flat == out[roi, c0:c0+NC, :] flat.
            float* ob = out + (size_t)roi * (CCH * NBIN) + (size_t)c0 * NBIN;
            for (int i = t; i < NC * NBIN; i += 256)
                ob[i] = s_out[i];
            // next chunk's compute (writes s_out) is separated from this dump
            // by the post-load __syncthreads above.
        }
    } else {
        // -------- fallback (window too large; not expected for this data) --------
        const int c = t;
        const float* fc = fb + (size_t)c * HW;
        float* ob = out + (size_t)roi * (CCH * NBIN) + (size_t)c * NBIN;
        for (int bin = 0; bin < NBIN; ++bin) {
            const int oy = bin / 7, ox = bin - (bin / 7) * 7;
            const int ia = 2 * oy, ib = ia + 1;
            const int ja = 2 * ox, jb = ja + 1;
            const int yA0 = s_ay0[ia] * W, yA1 = s_ay1[ia] * W;
            const int yB0 = s_ay0[ib] * W, yB1 = s_ay1[ib] * W;
            const int xA0 = s_ax0[ja], xA1 = s_ax1[ja];
            const int xB0 = s_ax0[jb], xB1 = s_ax1[jb];
            const float wyAh = s_wyh[ia], wyAl = s_wyl[ia];
            const float wyBh = s_wyh[ib], wyBl = s_wyl[ib];
            const float wxAh = s_wxh[ja], wxAl = s_wxl[ja];
            const float wxBh = s_wxh[jb], wxBl = s_wxl[jb];
            const float acc =
                wyAh * (wxAh * fc[yA0 + xA0] + wxAl * fc[yA0 + xA1])
              + wyAl * (wxAh * fc[yA1 + xA0] + wxAl * fc[yA1 + xA1])
              + wyAh * (wxBh * fc[yA0 + xB0] + wxBl * fc[yA0 + xB1])
              + wyAl * (wxBh * fc[yA1 + xB0] + wxBl * fc[yA1 + xB1])
              + wyBh * (wxAh * fc[yB0 + xA0] + wxAl * fc[yB0 + xA1])
              + wyBl * (wxAh * fc[yB1 + xA0] + wxAl * fc[yB1 + xA1])
              + wyBh * (wxBh * fc[yB0 + xB0] + wxBl * fc[yB0 + xB1])
              + wyBl * (wxBh * fc[yB1 + xB0] + wxBl * fc[yB1 + xB1]);
            ob[bin] = acc * 0.25f;
        }
    }
}

extern "C" void kernel_launch(void* const* d_in, const int* in_sizes, int n_in,
                              void* d_out, int out_size, void* d_ws, size_t ws_size,
                              hipStream_t stream) {
    const float* f0    = (const float*)d_in[0];
    const float* f1    = (const float*)d_in[1];
    const float* f2    = (const float*)d_in[2];
    const float* f3    = (const float*)d_in[3];
    const float* boxes = (const float*)d_in[4];
    float*       outp  = (float*)d_out;

    const int R = out_size / (CCH * NBIN);   // 512
    roi_direct<<<R, 256, 0, stream>>>(f0, f1, f2, f3, boxes, outp);
}

// Round 6
// 307.566 us; speedup vs baseline: 9.3834x; 9.3834x over previous
//
#include <hip/hip_runtime.h>

// ROIPooler (FPN multi-level ROIAlign, aligned=true), float32 in/out.
// R5: single-kernel direct-from-NCHW gather, chunk-parallel.
// Block = (roi, 8-channel chunk): stage the ROI's sample window (<= ~350 px,
// CAPP=513 cap) for 8 channels into LDS (half-wave per row-run, coalesced),
// one barrier, compute 49 bins x 8 ch from LDS, one barrier, coalesced dump.
// Grid 512x32 = 16384 blocks, ~18KB LDS -> high occupancy, 2 barriers/block.

#define OUTD 7
#define SRD  2
#define SD   14      // OUT*SR samples per axis
#define CCH  256
#define NBOX 256
#define NC   8       // channels per block
#define NCHK (CCH / NC)   // 32 chunks
#define CAPP 513     // window floats per channel (odd -> LDS bank spread)
#define NBIN (OUTD * OUTD)

__global__ __launch_bounds__(256) void roi_direct(
    const float* __restrict__ f0, const float* __restrict__ f1,
    const float* __restrict__ f2, const float* __restrict__ f3,
    const float* __restrict__ boxes, float* __restrict__ out)
{
    const int roi = blockIdx.x;
    const int c0  = blockIdx.y * NC;
    const int t   = threadIdx.x;
    const int b   = roi / NBOX;

    const float bx1 = boxes[roi * 4 + 0];
    const float by1 = boxes[roi * 4 + 1];
    const float bx2 = boxes[roi * 4 + 2];
    const float by2 = boxes[roi * 4 + 3];

    // Level assignment (block-uniform).
    const float area = (bx2 - bx1) * (by2 - by1);
    const float sz   = sqrtf(area);
    int lvl = (int)floorf(4.0f + log2f(sz * (1.0f / 224.0f) + 1e-8f));
    lvl = min(max(lvl, 2), 5) - 2;

    const int   H     = 256 >> lvl;
    const int   W     = H;
    const float scale = 1.0f / (float)(4 << lvl);
    const size_t HW   = (size_t)H * (size_t)W;

    const float* f  = (lvl == 0) ? f0 : (lvl == 1) ? f1 : (lvl == 2) ? f2 : f3;
    const float* fb = f + (size_t)b * CCH * HW;

    __shared__ int   s_ax0[SD], s_ax1[SD], s_ay0[SD], s_ay1[SD];
    __shared__ float s_wxh[SD], s_wxl[SD], s_wyh[SD], s_wyl[SD];
    __shared__ float s_win[NC * CAPP];   // 16416 B
    __shared__ float s_out[NC * NBIN];   // 1568 B

    if (t < SD) {
        const int i = t;
        const float x1r = bx1 * scale - 0.5f;
        const float y1r = by1 * scale - 0.5f;
        const float x2r = bx2 * scale - 0.5f;
        const float y2r = by2 * scale - 0.5f;
        const float bw = (x2r - x1r) * (1.0f / OUTD);
        const float bh = (y2r - y1r) * (1.0f / OUTD);
        const float g  = ((float)i + 0.5f) * (1.0f / SRD);
        const float ys = y1r + g * bh;
        const float xs = x1r + g * bw;
        const float vy = ((ys >= -1.0f) && (ys <= (float)H)) ? 1.0f : 0.0f;
        const float vx = ((xs >= -1.0f) && (xs <= (float)W)) ? 1.0f : 0.0f;
        const float yc = fminf(fmaxf(ys, 0.0f), (float)(H - 1));
        const float xc = fminf(fmaxf(xs, 0.0f), (float)(W - 1));
        const int y0 = (int)yc;
        const int x0 = (int)xc;
        const float ly = yc - (float)y0;
        const float lx = xc - (float)x0;
        s_ay0[i] = y0;
        s_ay1[i] = min(y0 + 1, H - 1);
        s_ax0[i] = x0;
        s_ax1[i] = min(x0 + 1, W - 1);
        s_wyh[i] = vy * (1.0f - ly);
        s_wyl[i] = vy * ly;
        s_wxh[i] = vx * (1.0f - lx);
        s_wxl[i] = vx * lx;
    }
    __syncthreads();

    // Window bounds (uniform across block; broadcast LDS reads).
    int x_lo = s_ax0[0], x_hi = s_ax1[0], y_lo = s_ay0[0], y_hi = s_ay1[0];
    #pragma unroll
    for (int j = 1; j < SD; ++j) {
        x_lo = min(x_lo, s_ax0[j]); x_hi = max(x_hi, s_ax1[j]);
        y_lo = min(y_lo, s_ay0[j]); y_hi = max(y_hi, s_ay1[j]);
    }
    const int Ww = x_hi - x_lo + 1;
    const int Hw = y_hi - y_lo + 1;

    // Thread -> (channel-group, bin) for compute/writeback.
    const int c_idx = t / 49;            // 0..5 (5 partial)
    const int bin   = t - c_idx * 49;
    const int oy    = bin / 7;
    const int ox    = bin - oy * 7;
    const int ia = 2 * oy, ib = ia + 1;
    const int ja = 2 * ox, jb = ja + 1;

    if (Hw * Ww <= CAPP) {
        // -------- fast path --------
        // Stage: half-wave (32 lanes) per row-run; runs = y*NC + c over 8 ch.
        const int hw   = t >> 5;         // 0..7
        const int l32  = t & 31;
        const int nruns = NC * Hw;
        for (int run = hw; run < nruns; run += 8) {
            const int c = run & (NC - 1);
            const int y = run >> 3;
            const float* src = fb + (size_t)(c0 + c) * HW
                                  + (size_t)(y_lo + y) * W + x_lo;
            float* dst = s_win + c * CAPP + y * Ww;
            for (int x = l32; x < Ww; x += 32)
                dst[x] = src[x];
        }
        __syncthreads();

        if (t < 245) {
            const int ryA0 = (s_ay0[ia] - y_lo) * Ww, ryA1 = (s_ay1[ia] - y_lo) * Ww;
            const int ryB0 = (s_ay0[ib] - y_lo) * Ww, ryB1 = (s_ay1[ib] - y_lo) * Ww;
            const int rxA0 = s_ax0[ja] - x_lo,        rxA1 = s_ax1[ja] - x_lo;
            const int rxB0 = s_ax0[jb] - x_lo,        rxB1 = s_ax1[jb] - x_lo;
            const float wyAh = s_wyh[ia], wyAl = s_wyl[ia];
            const float wyBh = s_wyh[ib], wyBl = s_wyl[ib];
            const float wxAh = s_wxh[ja], wxAl = s_wxl[ja];
            const float wxBh = s_wxh[jb], wxBl = s_wxl[jb];
            for (int ci = c_idx; ci < NC; ci += 5) {
                const float* w = s_win + ci * CAPP;
                const float acc =
                    wyAh * (wxAh * w[ryA0 + rxA0] + wxAl * w[ryA0 + rxA1])
                  + wyAl * (wxAh * w[ryA1 + rxA0] + wxAl * w[ryA1 + rxA1])
                  + wyAh * (wxBh * w[ryA0 + rxB0] + wxBl * w[ryA0 + rxB1])
                  + wyAl * (wxBh * w[ryA1 + rxB0] + wxBl * w[ryA1 + rxB1])
                  + wyBh * (wxAh * w[ryB0 + rxA0] + wxAl * w[ryB0 + rxA1])
                  + wyBl * (wxAh * w[ryB1 + rxA0] + wxAl * w[ryB1 + rxA1])
                  + wyBh * (wxBh * w[ryB0 + rxB0] + wxBl * w[ryB0 + rxB1])
                  + wyBl * (wxBh * w[ryB1 + rxB0] + wxBl * w[ryB1 + rxB1]);
                s_out[ci * NBIN + bin] = acc * 0.25f;
            }
        }
        __syncthreads();

        // Coalesced dump: s_out flat == out[roi, c0:c0+NC, :] flat (1568 B).
        float* ob = out + (size_t)roi * (CCH * NBIN) + (size_t)c0 * NBIN;
        for (int i = t; i < NC * NBIN; i += 256)
            ob[i] = s_out[i];
    } else {
        // -------- fallback: direct global gather for this chunk --------
        const int yA0g = s_ay0[ia] * W, yA1g = s_ay1[ia] * W;
        const int yB0g = s_ay0[ib] * W, yB1g = s_ay1[ib] * W;
        const int xA0 = s_ax0[ja], xA1 = s_ax1[ja];
        const int xB0 = s_ax0[jb], xB1 = s_ax1[jb];
        const float wyAh = s_wyh[ia], wyAl = s_wyl[ia];
        const float wyBh = s_wyh[ib], wyBl = s_wyl[ib];
        const float wxAh = s_wxh[ja], wxAl = s_wxl[ja];
        const float wxBh = s_wxh[jb], wxBl = s_wxl[jb];
        float* ob = out + (size_t)roi * (CCH * NBIN) + (size_t)c0 * NBIN;
        for (int idx = t; idx < NC * NBIN; idx += 256) {
            const int ci = idx / NBIN;
            const int bn = idx - ci * NBIN;
            const int oy2 = bn / 7, ox2 = bn - (bn / 7) * 7;
            const int i2a = 2 * oy2, i2b = i2a + 1;
            const int j2a = 2 * ox2, j2b = j2a + 1;
            const float* fc = fb + (size_t)(c0 + ci) * HW;
            const float acc =
                s_wyh[i2a] * (s_wxh[j2a] * fc[s_ay0[i2a] * W + s_ax0[j2a]] + s_wxl[j2a] * fc[s_ay0[i2a] * W + s_ax1[j2a]])
              + s_wyl[i2a] * (s_wxh[j2a] * fc[s_ay1[i2a] * W + s_ax0[j2a]] + s_wxl[j2a] * fc[s_ay1[i2a] * W + s_ax1[j2a]])
              + s_wyh[i2a] * (s_wxh[j2b] * fc[s_ay0[i2a] * W + s_ax0[j2b]] + s_wxl[j2b] * fc[s_ay0[i2a] * W + s_ax1[j2b]])
              + s_wyl[i2a] * (s_wxh[j2b] * fc[s_ay1[i2a] * W + s_ax0[j2b]] + s_wxl[j2b] * fc[s_ay1[i2a] * W + s_ax1[j2b]])
              + s_wyh[i2b] * (s_wxh[j2a] * fc[s_ay0[i2b] * W + s_ax0[j2a]] + s_wxl[j2a] * fc[s_ay0[i2b] * W + s_ax1[j2a]])
              + s_wyl[i2b] * (s_wxh[j2a] * fc[s_ay1[i2b] * W + s_ax0[j2a]] + s_wxl[j2a] * fc[s_ay1[i2b] * W + s_ax1[j2a]])
              + s_wyh[i2b] * (s_wxh[j2b] * fc[s_ay0[i2b] * W + s_ax0[j2b]] + s_wxl[j2b] * fc[s_ay0[i2b] * W + s_ax1[j2b]])
              + s_wyl[i2b] * (s_wxh[j2b] * fc[s_ay1[i2b] * W + s_ax0[j2b]] + s_wxl[j2b] * fc[s_ay1[i2b] * W + s_ax1[j2b]]);
            ob[idx] = acc * 0.25f;
        }
        (void)yA0g; (void)yA1g; (void)yB0g; (void)yB1g;
        (void)xA0; (void)xA1; (void)xB0; (void)xB1;
        (void)wyAh; (void)wyAl; (void)wyBh; (void)wyBl;
        (void)wxAh; (void)wxAl; (void)wxBh; (void)wxBl;
    }
}

extern "C" void kernel_launch(void* const* d_in, const int* in_sizes, int n_in,
                              void* d_out, int out_size, void* d_ws, size_t ws_size,
                              hipStream_t stream) {
    const float* f0    = (const float*)d_in[0];
    const float* f1    = (const float*)d_in[1];
    const float* f2    = (const float*)d_in[2];
    const float* f3    = (const float*)d_in[3];
    const float* boxes = (const float*)d_in[4];
    float*       outp  = (float*)d_out;

    const int R = out_size / (CCH * NBIN);   // 512
    roi_direct<<<dim3(R, NCHK), 256, 0, stream>>>(f0, f1, f2, f3, boxes, outp);
}